// Round 6
// baseline (565.399 us; speedup 1.0000x reference)
//
#include <hip/hip_runtime.h>
#include <hip/hip_bf16.h>

// ---------------------------------------------------------------------------
// SingleHeadAttention: b=8, t=2048, e=1024. I/O = float32.
//   Q = (q @ Wq^T)/e^0.25 ; K = (k @ Wk^T)/e^0.25 ; V = v @ Wv^T
//   S = Q K^T (causal) ; P = softmax(S) ; O = P V
// bf16 MFMA internals, f32 accumulate, f32 output.
//
// Round-6: DOUBLE-BUFFERED async K-loops (1 barrier per K-step). Prefetch
// tile k+1 via global_load_lds into the idle LDS half while MFMAing tile k;
// the vmcnt(0) drain at the next barrier has had a full MFMA phase to
// complete. BK=32 everywhere keeps dbuf LDS small: proj 48 KB (3 blk/CU),
// score/out 32 KB (4+ blk/CU). XOR-swizzled LDS (16B granules) retained.
//  - ws: [Q][K][Vt][S]; bf16 weights alias the dead S region during proj.
// ---------------------------------------------------------------------------

typedef short short8 __attribute__((ext_vector_type(8)));   // 8 x bf16
typedef float f32x4 __attribute__((ext_vector_type(4)));
typedef int   int4v __attribute__((ext_vector_type(4)));

static constexpr int B_ = 8;
static constexpr int T_ = 2048;
static constexpr int E_ = 1024;

__device__ __forceinline__ float bf2f(ushort u) {
    union { unsigned int i; float f; } x; x.i = ((unsigned int)u) << 16; return x.f;
}
__device__ __forceinline__ ushort f2bf(float f) {
    union { float f; unsigned int i; } x; x.f = f;
    unsigned int r = x.i + 0x7fffu + ((x.i >> 16) & 1u);   // RNE
    return (ushort)(r >> 16);
}
// packed f32x8 -> bf16x8 (RNE)
__device__ __forceinline__ short8 cvt8(f32x4 a, f32x4 b) {
    short8 r;
    union { __hip_bfloat162 h; unsigned int u; } p;
    unsigned int* ru = (unsigned int*)&r;
    p.h = __float22bfloat162_rn(make_float2(a[0], a[1])); ru[0] = p.u;
    p.h = __float22bfloat162_rn(make_float2(a[2], a[3])); ru[1] = p.u;
    p.h = __float22bfloat162_rn(make_float2(b[0], b[1])); ru[2] = p.u;
    p.h = __float22bfloat162_rn(make_float2(b[2], b[3])); ru[3] = p.u;
    return r;
}

// async 16B global -> LDS; lds base wave-uniform, lane i lands at +16*i.
__device__ __forceinline__ void async16(const ushort* g, ushort* l) {
    __builtin_amdgcn_global_load_lds(
        (const __attribute__((address_space(1))) unsigned int*)g,
        (__attribute__((address_space(3))) unsigned int*)l, 16, 0, 0);
}
__device__ __forceinline__ void async16f(const float* g, float* l) {
    __builtin_amdgcn_global_load_lds(
        (const __attribute__((address_space(1))) unsigned int*)g,
        (__attribute__((address_space(3))) unsigned int*)l, 16, 0, 0);
}

// ---------------------------------------------------------------------------
// Double-buffered BK=32 NT GEMM: C[128x128] += A[128xK] * B[128xK]^T, bf16.
// LDS halves of 128x32 each (8 KB); row = 4 granules of 16B, swizzle
// g ^= (r>>1)&3. One __syncthreads per K-step; stage(ks+1) overlaps MFMA(ks).
__device__ __forceinline__ void gemm32_db(const ushort* __restrict__ A, int lda,
                                          const ushort* __restrict__ Bm, int ldb,
                                          int ksteps, f32x4 (&acc)[4][4],
                                          ushort* As, ushort* Bs)  // 2x4096 each
{
    const int tid = threadIdx.x, lane = tid & 63, wave = tid >> 6;
    const int wr = (wave >> 1) * 64, wc = (wave & 1) * 64;
    const int sr = lane >> 2;                              // row in 16-row chunk
    const int sc = ((lane & 3) ^ ((lane >> 3) & 3)) * 8;   // swizzled src col
    const int frow = lane & 15, q4 = lane >> 4;
    const int gsw = (q4 ^ ((frow >> 1) & 3)) * 8;          // frag granule offset

    int cur = 0;
    {   // preload ks = 0 into half 0
#pragma unroll
        for (int j = 0; j < 2; ++j) {
            const int c = wave * 2 + j;
            const int grow = c * 16 + sr;
            async16(A  + (size_t)grow * lda + sc, As + c * 512);
            async16(Bm + (size_t)grow * ldb + sc, Bs + c * 512);
        }
    }
    for (int ks = 0; ks < ksteps; ++ks) {
        __syncthreads();   // drains vmcnt(0): buf[cur] ready; prior reads done
        if (ks + 1 < ksteps) {
            const int k0 = (ks + 1) * 32;
            ushort* as = As + (cur ^ 1) * 4096;
            ushort* bs = Bs + (cur ^ 1) * 4096;
#pragma unroll
            for (int j = 0; j < 2; ++j) {
                const int c = wave * 2 + j;
                const int grow = c * 16 + sr;
                async16(A  + (size_t)grow * lda + k0 + sc, as + c * 512);
                async16(Bm + (size_t)grow * ldb + k0 + sc, bs + c * 512);
            }
        }
        const ushort* as = As + cur * 4096;
        const ushort* bs = Bs + cur * 4096;
        short8 af[4], bf[4];
#pragma unroll
        for (int i = 0; i < 4; ++i) {
            af[i] = *(const short8*)(as + (wr + i * 16 + frow) * 32 + gsw);
            bf[i] = *(const short8*)(bs + (wc + i * 16 + frow) * 32 + gsw);
        }
#pragma unroll
        for (int mi = 0; mi < 4; ++mi)
#pragma unroll
            for (int ni = 0; ni < 4; ++ni)
                acc[mi][ni] = __builtin_amdgcn_mfma_f32_16x16x32_bf16(
                    af[mi], bf[ni], acc[mi][ni], 0, 0, 0);
        cur ^= 1;
    }
}

// ---------------------------------------------------------------------------
// Weight converter: three 1024x1024 f32 -> bf16 (grid.y = 3).
__global__ __launch_bounds__(256)
void cvtW_kernel(const float* __restrict__ w0, const float* __restrict__ w1,
                 const float* __restrict__ w2, ushort* __restrict__ d)
{
    const float* s = blockIdx.y == 0 ? w0 : (blockIdx.y == 1 ? w1 : w2);
    ushort* dd = d + (size_t)blockIdx.y * E_ * E_;
    const int idx = (blockIdx.x * 256 + threadIdx.x) * 8;
    f32x4 a = *(const f32x4*)(s + idx);
    f32x4 b = *(const f32x4*)(s + idx + 4);
    *(short8*)(dd + idx) = cvt8(a, b);
}

// ---------------------------------------------------------------------------
// Stage 1: all three projections, one dispatch. grid (128, 8, 3). BK=32,
// double-buffered. A (f32) staged async into swizzled f32 LDS (8 granules/row,
// swz r&7); B (bf16) 4 granules/row, swz (r>>1)&3. 48 KB LDS -> 3 blocks/CU.
__global__ __launch_bounds__(256, 3)
void proj_kernel(const float* __restrict__ q, const float* __restrict__ k,
                 const float* __restrict__ v, const ushort* __restrict__ Wb,
                 ushort* __restrict__ Q, ushort* __restrict__ Kp,
                 ushort* __restrict__ Vt)
{
    __shared__ float  Asf[2 * 128 * 32];   // 32 KB
    __shared__ ushort Bs[2 * 128 * 32];    // 16 KB
    const int z = blockIdx.z;
    const float* A = (z == 0 ? q : (z == 1 ? k : v)) + (size_t)blockIdx.x * 128 * E_;
    const ushort* W = Wb + (size_t)z * E_ * E_ + (size_t)blockIdx.y * 128 * E_;

    const int tid = threadIdx.x, lane = tid & 63, wave = tid >> 6;
    const int wr = (wave >> 1) * 64, wc = (wave & 1) * 64;
    const int sArow = lane >> 3;
    const int sAcol = ((lane & 7) ^ sArow) * 4;
    const int sBrow = lane >> 2;
    const int sBcol = ((lane & 3) ^ ((lane >> 3) & 3)) * 8;
    const int frow = lane & 15, q4 = lane >> 4;
    const int gB = (q4 ^ ((frow >> 1) & 3)) * 8;

    f32x4 acc[4][4];
#pragma unroll
    for (int i = 0; i < 4; ++i)
#pragma unroll
        for (int j = 0; j < 4; ++j) acc[i][j] = (f32x4){0.f, 0.f, 0.f, 0.f};

    int cur = 0;
    {   // preload ks = 0
#pragma unroll
        for (int j = 0; j < 4; ++j) {
            const int c = wave * 4 + j;
            async16f(A + (size_t)(c * 8 + sArow) * E_ + sAcol, Asf + c * 256);
        }
#pragma unroll
        for (int j = 0; j < 2; ++j) {
            const int c = wave * 2 + j;
            async16(W + (size_t)(c * 16 + sBrow) * E_ + sBcol, Bs + c * 512);
        }
    }
    for (int ks = 0; ks < E_ / 32; ++ks) {
        __syncthreads();
        if (ks + 1 < E_ / 32) {
            const int k0 = (ks + 1) * 32;
            float*  asf = Asf + (cur ^ 1) * 4096;
            ushort* bs  = Bs  + (cur ^ 1) * 4096;
#pragma unroll
            for (int j = 0; j < 4; ++j) {
                const int c = wave * 4 + j;
                async16f(A + (size_t)(c * 8 + sArow) * E_ + k0 + sAcol, asf + c * 256);
            }
#pragma unroll
            for (int j = 0; j < 2; ++j) {
                const int c = wave * 2 + j;
                async16(W + (size_t)(c * 16 + sBrow) * E_ + k0 + sBcol, bs + c * 512);
            }
        }
        const float*  asf = Asf + cur * 4096;
        const ushort* bs  = Bs  + cur * 4096;
        short8 af[4], bf[4];
#pragma unroll
        for (int i = 0; i < 4; ++i) {
            const int R = wr + i * 16 + frow;
            const int g0 = (q4 * 2) ^ (frow & 7);
            f32x4 lo = *(const f32x4*)(asf + R * 32 + g0 * 4);
            f32x4 hi = *(const f32x4*)(asf + R * 32 + (g0 ^ 1) * 4);
            af[i] = cvt8(lo, hi);
        }
#pragma unroll
        for (int i = 0; i < 4; ++i)
            bf[i] = *(const short8*)(bs + (wc + i * 16 + frow) * 32 + gB);
#pragma unroll
        for (int mi = 0; mi < 4; ++mi)
#pragma unroll
            for (int ni = 0; ni < 4; ++ni)
                acc[mi][ni] = __builtin_amdgcn_mfma_f32_16x16x32_bf16(
                    af[mi], bf[ni], acc[mi][ni], 0, 0, 0);
        cur ^= 1;
    }

    const float scale = (z == 2) ? 1.0f : 0.17677669529663687f;  // 1/e^(1/4)
    if (z < 2) {
        ushort* D = (z == 0 ? Q : Kp);
#pragma unroll
        for (int mi = 0; mi < 4; ++mi)
#pragma unroll
            for (int r = 0; r < 4; ++r) {
                const int row = blockIdx.x * 128 + wr + mi * 16 + (lane >> 4) * 4 + r;
#pragma unroll
                for (int ni = 0; ni < 4; ++ni) {
                    const int col = blockIdx.y * 128 + wc + ni * 16 + (lane & 15);
                    D[(size_t)row * E_ + col] = f2bf(acc[mi][ni][r] * scale);
                }
            }
    } else {
#pragma unroll
        for (int mi = 0; mi < 4; ++mi)
#pragma unroll
            for (int r = 0; r < 4; ++r) {
                const int rowg = blockIdx.x * 128 + wr + mi * 16 + (lane >> 4) * 4 + r;
                const int bb = rowg >> 11, tl = rowg & 2047;
#pragma unroll
                for (int ni = 0; ni < 4; ++ni) {
                    const int col = blockIdx.y * 128 + wc + ni * 16 + (lane & 15);
                    Vt[(size_t)bb * E_ * T_ + (size_t)col * T_ + tl] = f2bf(acc[mi][ni][r]);
                }
            }
    }
}

// ---------------------------------------------------------------------------
// Stage 2: S = Q K^T causal. Compact lower-triangle grid (136, 8). dbuf BK=32.
__global__ __launch_bounds__(256, 4)
void score_kernel(const ushort* __restrict__ Q, const ushort* __restrict__ K,
                  ushort* __restrict__ S)
{
    __shared__ ushort As[2 * 128 * 32];   // 16 KB
    __shared__ ushort Bs[2 * 128 * 32];   // 16 KB
    const int t = blockIdx.x, b = blockIdx.y;
    int br = (int)((sqrtf(8.0f * t + 1.0f) - 1.0f) * 0.5f);
    while ((br + 1) * (br + 2) / 2 <= t) ++br;
    while (br * (br + 1) / 2 > t) --br;
    const int bc = t - br * (br + 1) / 2;

    const ushort* A  = Q + ((size_t)b * T_ + br * 128) * E_;
    const ushort* Bm = K + ((size_t)b * T_ + bc * 128) * E_;

    f32x4 acc[4][4];
#pragma unroll
    for (int i = 0; i < 4; ++i)
#pragma unroll
        for (int j = 0; j < 4; ++j) acc[i][j] = (f32x4){0.f, 0.f, 0.f, 0.f};

    gemm32_db(A, E_, Bm, E_, E_ / 32, acc, As, Bs);

    const int lane = threadIdx.x & 63, wave = threadIdx.x >> 6;
    const int wr = (wave >> 1) * 64, wc = (wave & 1) * 64;
    ushort* Sb = S + (size_t)b * T_ * T_;
#pragma unroll
    for (int mi = 0; mi < 4; ++mi)
#pragma unroll
        for (int r = 0; r < 4; ++r) {
            const int row = br * 128 + wr + mi * 16 + (lane >> 4) * 4 + r;
#pragma unroll
            for (int ni = 0; ni < 4; ++ni) {
                const int col = bc * 128 + wc + ni * 16 + (lane & 15);
                float val = acc[mi][ni][r];
                if (col > row) val = -1e30f;
                Sb[(size_t)row * T_ + col] = f2bf(val);
            }
        }
}

// ---------------------------------------------------------------------------
// Stage 3: row softmax in place, 16B vector I/O. One block per row.
__global__ __launch_bounds__(256)
void softmax_kernel(ushort* __restrict__ S)
{
    const int gr = blockIdx.x;
    const int b = gr >> 11, i = gr & 2047;
    ushort* row = S + (size_t)b * T_ * T_ + (size_t)i * T_;
    const int Lpad = ((i >> 7) + 1) * 128;
    const int tid = threadIdx.x, lane = tid & 63, wave = tid >> 6;
    __shared__ float red[4];

    const int j0 = tid * 8;
    const bool act = j0 < Lpad;
    float xv[8];
    if (act) {
        int4v dv = *(const int4v*)(row + j0);
        const ushort* u = (const ushort*)&dv;
#pragma unroll
        for (int t = 0; t < 8; ++t) xv[t] = bf2f(u[t]);
    }

    float m = -1e30f;
    if (act)
#pragma unroll
        for (int t = 0; t < 8; ++t) m = fmaxf(m, xv[t]);
#pragma unroll
    for (int o = 32; o; o >>= 1) m = fmaxf(m, __shfl_xor(m, o, 64));
    if (lane == 0) red[wave] = m;
    __syncthreads();
    m = fmaxf(fmaxf(red[0], red[1]), fmaxf(red[2], red[3]));
    __syncthreads();

    float s = 0.f;
    if (act)
#pragma unroll
        for (int t = 0; t < 8; ++t) { xv[t] = __expf(xv[t] - m); s += xv[t]; }
#pragma unroll
    for (int o = 32; o; o >>= 1) s += __shfl_xor(s, o, 64);
    if (lane == 0) red[wave] = s;
    __syncthreads();
    s = red[0] + red[1] + red[2] + red[3];
    const float inv = 1.0f / s;

    if (act) {
        int4v dv;
        ushort* u = (ushort*)&dv;
#pragma unroll
        for (int t = 0; t < 8; ++t) u[t] = f2bf(xv[t] * inv);
        *(int4v*)(row + j0) = dv;
    }
}

// ---------------------------------------------------------------------------
// Stage 4: O = P @ V via V^T (NT, dbuf BK=32). grid (8, 16, 8). f32 output.
__global__ __launch_bounds__(256, 4)
void out_kernel(const ushort* __restrict__ P, const ushort* __restrict__ Vt,
                float* __restrict__ O)
{
    __shared__ ushort As[2 * 128 * 32];
    __shared__ ushort Bs[2 * 128 * 32];
    const int bc = blockIdx.x, br = blockIdx.y, b = blockIdx.z;
    const ushort* A  = P  + (size_t)b * T_ * T_ + (size_t)(br * 128) * T_;
    const ushort* Bm = Vt + (size_t)b * E_ * T_ + (size_t)(bc * 128) * T_;
    const int ksteps = (br + 1) * 4;   // causal K-limit, BK=32

    f32x4 acc[4][4];
#pragma unroll
    for (int i = 0; i < 4; ++i)
#pragma unroll
        for (int j = 0; j < 4; ++j) acc[i][j] = (f32x4){0.f, 0.f, 0.f, 0.f};

    gemm32_db(A, T_, Bm, T_, ksteps, acc, As, Bs);

    const int lane = threadIdx.x & 63, wave = threadIdx.x >> 6;
    const int wr = (wave >> 1) * 64, wc = (wave & 1) * 64;
    float* Ob = O + (size_t)b * T_ * E_;
#pragma unroll
    for (int mi = 0; mi < 4; ++mi)
#pragma unroll
        for (int r = 0; r < 4; ++r) {
            const int row = br * 128 + wr + mi * 16 + (lane >> 4) * 4 + r;
#pragma unroll
            for (int ni = 0; ni < 4; ++ni) {
                const int col = bc * 128 + wc + ni * 16 + (lane & 15);
                Ob[(size_t)row * E_ + col] = acc[mi][ni][r];
            }
        }
}

// ---------------------------------------------------------------------------
extern "C" void kernel_launch(void* const* d_in, const int* in_sizes, int n_in,
                              void* d_out, int out_size, void* d_ws, size_t ws_size,
                              hipStream_t stream)
{
    const float* q  = (const float*)d_in[0];
    const float* k  = (const float*)d_in[1];
    const float* v  = (const float*)d_in[2];
    const float* Wq = (const float*)d_in[3];
    const float* Wk = (const float*)d_in[4];
    const float* Wv = (const float*)d_in[5];
    float* out = (float*)d_out;

    const size_t nQKV = (size_t)B_ * T_ * E_;      // 16,777,216 elems
    const size_t nW   = (size_t)E_ * E_;
    ushort* Q  = (ushort*)d_ws;
    ushort* K  = Q + nQKV;
    ushort* Vt = K + nQKV;
    ushort* S  = Vt + nQKV;                        // 67 MB
    ushort* Wb = S;                                // weights alias dead S region

    cvtW_kernel<<<dim3(nW / 2048, 3), 256, 0, stream>>>(Wq, Wk, Wv, Wb);
    proj_kernel<<<dim3(128, 8, 3), 256, 0, stream>>>(q, k, v, Wb, Q, K, Vt);
    score_kernel<<<dim3(136, B_), 256, 0, stream>>>(Q, K, S);
    softmax_kernel<<<dim3(B_ * T_), 256, 0, stream>>>(S);
    out_kernel<<<dim3(E_ / 128, T_ / 128, B_), 256, 0, stream>>>(S, Vt, out);
}